// Round 12
// baseline (38.809 us; speedup 1.0000x reference)
//
#include <hip/hip_runtime.h>
#include <hip/hip_bf16.h>

typedef __attribute__((ext_vector_type(8))) short bf16x8;
typedef __attribute__((ext_vector_type(4))) float f32x4;

__device__ __forceinline__ unsigned short f2bf(float f) {
    union { float f; unsigned int u; } v; v.f = f;
    unsigned int u = v.u;
    unsigned int r = u + 0x7FFFu + ((u >> 16) & 1u);   // RNE
    return (unsigned short)(r >> 16);
}

__device__ __forceinline__ unsigned int cvtpk(float lo, float hi) {
    unsigned int r;
    asm("v_cvt_pk_bf16_f32 %0, %1, %2" : "=v"(r) : "v"(lo), "v"(hi));
    return r;
}

__device__ __forceinline__ float frcp(float x) {
    float r;
    asm("v_rcp_f32 %0, %1" : "=v"(r) : "v"(x));
    return r;
}

#define GLDS16(gsrc, ldst)                                                          \
    __builtin_amdgcn_global_load_lds(                                               \
        (const __attribute__((address_space(1))) unsigned int*)(gsrc),              \
        (__attribute__((address_space(3))) unsigned int*)(ldst), 16, 0, 0)

// ---------------- kernel 0: W -> Wt2, sigma-permuted k within each 32-chunk --------
// MFMA contracts positionally: A k-slot (lg,e) pairs with B k-slot (lg,e).
// x is loaded DENSELY: lane lg reads floats lg*4..lg*4+3 (instr 0) and
// 16+lg*4.. (instr 1) -> sigma(lg,e) = (e<4?0:16) + lg*4 + (e&3).
// Wt2[c][lg][col][e] = W[c*32 + sigma(lg,e)][col] makes the GEMM exact.
__global__ __launch_bounds__(256) void wprep(const float* __restrict__ Wq,
                                             const float* __restrict__ Wk,
                                             const float* __restrict__ Wv,
                                             unsigned short* __restrict__ Wt2) {
    int idx = blockIdx.x * 256 + threadIdx.x;          // 3*64*384 = 73728
    if (idx >= 73728) return;
    int w   = idx / 24576;
    int rem = idx % 24576;
    int n = rem / 384, k = rem % 384;
    const float* W = (w == 0) ? Wq : ((w == 1) ? Wk : Wv);
    int col = w * 64 + n;
    int c = k >> 5, r = k & 31;
    int rr = r & 15;
    int lg = rr >> 2;
    int e  = ((r < 16) ? 0 : 4) + (rr & 3);
    Wt2[(size_t)c * 6144 + lg * 1536 + col * 8 + e] = f2bf(W[k * 64 + n]);
}

#define QOFF  0
#define KOFF  36864
#define VTOFF 73728
#define POFF  107520

// ---------------- phase 2 helper: 16-row strip, NT causal 64-col tiles --------------
template<int NT>
__device__ __forceinline__ void attn_strip16(char* smem, char* Pw, float* __restrict__ ob,
                                             int r0, int lane) {
    const int l15 = lane & 15, lg = lane >> 4;
    const float scale = 0.05103103630798287f;          // 384^-0.5

    bf16x8 aq[2];
#pragma unroll
    for (int kk = 0; kk < 2; ++kk)
        aq[kk] = *reinterpret_cast<const bf16x8*>(smem + QOFF + ((r0 + l15) * 72 + kk * 32 + lg * 8) * 2);

    f32x4 s[NT][4] = {};
#pragma unroll
    for (int jt = 0; jt < NT; ++jt)
#pragma unroll
        for (int kk = 0; kk < 2; ++kk) {
            bf16x8 bk[4];
#pragma unroll
            for (int n = 0; n < 4; ++n)
                bk[n] = *reinterpret_cast<const bf16x8*>(smem + KOFF + ((jt * 64 + n * 16 + l15) * 72 + kk * 32 + lg * 8) * 2);
#pragma unroll
            for (int n = 0; n < 4; ++n)
                s[jt][n] = __builtin_amdgcn_mfma_f32_16x16x32_bf16(aq[kk], bk[n], s[jt][n], 0, 0, 0);
        }

    float M[4];
#pragma unroll
    for (int j = 0; j < 4; ++j) M[j] = -1e30f;
#pragma unroll
    for (int jt = 0; jt < NT; ++jt)
#pragma unroll
        for (int n = 0; n < 4; ++n) {
            int colg = jt * 64 + n * 16 + l15;
#pragma unroll
            for (int j = 0; j < 4; ++j) {
                float v = s[jt][n][j] * scale;
                if (jt == NT - 1) {                     // earlier tiles statically valid
                    int rowg = r0 + lg * 4 + j;
                    if (colg > rowg) v = -1e30f;
                }
                s[jt][n][j] = v;
                M[j] = fmaxf(M[j], v);
            }
        }
#pragma unroll
    for (int j = 0; j < 4; ++j) {
        float v = M[j];
        v = fmaxf(v, __shfl_xor(v, 1));
        v = fmaxf(v, __shfl_xor(v, 2));
        v = fmaxf(v, __shfl_xor(v, 4));
        v = fmaxf(v, __shfl_xor(v, 8));
        M[j] = v;
    }
    float L[4] = {};
#pragma unroll
    for (int jt = 0; jt < NT; ++jt)
#pragma unroll
        for (int n = 0; n < 4; ++n)
#pragma unroll
            for (int j = 0; j < 4; ++j) {
                float p = __expf(s[jt][n][j] - M[j]);
                s[jt][n][j] = p;
                L[j] += p;
            }
    float rL[4];
#pragma unroll
    for (int j = 0; j < 4; ++j) {
        float v = L[j];
        v += __shfl_xor(v, 1);
        v += __shfl_xor(v, 2);
        v += __shfl_xor(v, 4);
        v += __shfl_xor(v, 8);
        rL[j] = frcp(v);
    }
    f32x4 o[4] = {};
#pragma unroll
    for (int jt = 0; jt < NT; ++jt) {
#pragma unroll
        for (int n = 0; n < 4; ++n)
#pragma unroll
            for (int j = 0; j < 4; ++j)
                *reinterpret_cast<unsigned short*>(Pw + ((lg * 4 + j) * 72 + n * 16 + l15) * 2) = f2bf(s[jt][n][j]);
        asm volatile("s_waitcnt lgkmcnt(0)" ::: "memory");   // wave-internal LDS RAW fence
#pragma unroll
        for (int kk = 0; kk < 2; ++kk) {
            bf16x8 ap, bv[4];
            ap = *reinterpret_cast<const bf16x8*>(Pw + (l15 * 72 + kk * 32 + lg * 8) * 2);
#pragma unroll
            for (int n = 0; n < 4; ++n)
                bv[n] = *reinterpret_cast<const bf16x8*>(smem + VTOFF + ((n * 16 + l15) * 264 + jt * 64 + kk * 32 + lg * 8) * 2);
#pragma unroll
            for (int n = 0; n < 4; ++n)
                o[n] = __builtin_amdgcn_mfma_f32_16x16x32_bf16(ap, bv[n], o[n], 0, 0, 0);
        }
    }
    // coalesced epilogue via padded f32 LDS tile (reuses Pw)
    float* tf = reinterpret_cast<float*>(Pw);
#pragma unroll
    for (int n = 0; n < 4; ++n)
#pragma unroll
        for (int j = 0; j < 4; ++j)
            tf[(lg * 4 + j) * 68 + n * 16 + l15] = o[n][j] * rL[j];
    asm volatile("s_waitcnt lgkmcnt(0)" ::: "memory");
#pragma unroll
    for (int i = 0; i < 4; ++i) {
        int row = i * 4 + lg;
        float4 vv = *reinterpret_cast<const float4*>(&tf[row * 68 + l15 * 4]);
        *reinterpret_cast<float4*>(ob + (size_t)(r0 + row) * 64 + l15 * 4) = vv;
    }
}

// ---------------- fused kernel: one block per batch, 512 threads / 8 waves ----------
__global__ __launch_bounds__(512, 1) void fused(const float* __restrict__ x,
                                                const unsigned short* __restrict__ Wt2,
                                                float* __restrict__ out) {
    __shared__ __align__(16) char smem[147456];

    const int b = blockIdx.x;
    const int tid = threadIdx.x, lane = tid & 63, wid = tid >> 6;   // wid 0..7
    const int l15 = lane & 15, lg = lane >> 4;
    const float* xb = x + (size_t)b * 98304;
    float* ob = out + (size_t)b * 16384;

    // ---- stage ALL of B once: 18 glds/wave, linear ----
#pragma unroll
    for (int i = 0; i < 18; ++i) {
        int n = wid * 18 + i;
        GLDS16(Wt2 + (size_t)n * 512 + lane * 8, smem + n * 1024);
    }

    // ---- x pointer: DENSE loads — lane lg covers floats lg*4..lg*4+3 of each chunk half
    const float* xw = xb + (size_t)(wid * 32 + l15) * 384 + lg * 4;

    float4 p0[4], p1[4], p2[4], p3[4], p4[4];
#define XLOAD(P, C)                                                                 \
    P[0] = *reinterpret_cast<const float4*>(xw + (C) * 32);                         \
    P[1] = *reinterpret_cast<const float4*>(xw + (C) * 32 + 16);                    \
    P[2] = *reinterpret_cast<const float4*>(xw + 6144 + (C) * 32);                  \
    P[3] = *reinterpret_cast<const float4*>(xw + 6144 + (C) * 32 + 16);
    XLOAD(p0, 0)
    XLOAD(p1, 1)
    XLOAD(p2, 2)
    XLOAD(p3, 3)
    XLOAD(p4, 4)
    __builtin_amdgcn_sched_barrier(0);
    asm volatile("s_waitcnt vmcnt(20)" ::: "memory");   // 18 B glds landed; x 0..4 in flight
    __builtin_amdgcn_s_barrier();                       // B visible to all waves

    f32x4 acc[2][12] = {};

#define CHUNK(C, P, WAITN)                                                          \
    asm volatile("s_waitcnt vmcnt(" #WAITN ")" ::: "memory");                       \
    __builtin_amdgcn_sched_barrier(0);                                              \
    {                                                                               \
        union { unsigned int u[4]; bf16x8 v; } cv0, cv1;                            \
        cv0.u[0] = cvtpk(P[0].x, P[0].y); cv0.u[1] = cvtpk(P[0].z, P[0].w);         \
        cv0.u[2] = cvtpk(P[1].x, P[1].y); cv0.u[3] = cvtpk(P[1].z, P[1].w);         \
        cv1.u[0] = cvtpk(P[2].x, P[2].y); cv1.u[1] = cvtpk(P[2].z, P[2].w);         \
        cv1.u[2] = cvtpk(P[3].x, P[3].y); cv1.u[3] = cvtpk(P[3].z, P[3].w);         \
        bf16x8 a0 = cv0.v, a1 = cv1.v;                                              \
        if ((C) + 5 < 12) { XLOAD(P, (C) + 5) }                                     \
        __builtin_amdgcn_sched_barrier(0);                                          \
        const char* bs = smem + (C) * 12288 + lg * 3072 + l15 * 16;                 \
        _Pragma("unroll")                                                           \
        for (int n = 0; n < 12; ++n) {                                              \
            bf16x8 bf = *reinterpret_cast<const bf16x8*>(bs + n * 256);             \
            acc[0][n] = __builtin_amdgcn_mfma_f32_16x16x32_bf16(a0, bf, acc[0][n], 0, 0, 0); \
            acc[1][n] = __builtin_amdgcn_mfma_f32_16x16x32_bf16(a1, bf, acc[1][n], 0, 0, 0); \
        }                                                                           \
    }

    CHUNK(0,  p0, 16)
    CHUNK(1,  p1, 16)
    CHUNK(2,  p2, 16)
    CHUNK(3,  p3, 16)
    CHUNK(4,  p4, 16)
    CHUNK(5,  p0, 16)
    CHUNK(6,  p1, 16)
    CHUNK(7,  p2, 16)
    CHUNK(8,  p3, 12)
    CHUNK(9,  p4, 8)
    CHUNK(10, p0, 4)
    CHUNK(11, p1, 0)

    __syncthreads();                                    // all waves done reading B

    // ---- stage Q/K/VT to LDS (C/D layout: col=l15, row=lg*4+j) ----
#pragma unroll
    for (int m = 0; m < 2; ++m) {
        const int t0 = wid * 32 + m * 16 + lg * 4;
#pragma unroll
        for (int n = 0; n < 4; ++n) {                   // Q cols 0..63
            int col = n * 16 + l15;
#pragma unroll
            for (int j = 0; j < 4; ++j)
                *reinterpret_cast<unsigned short*>(smem + QOFF + ((t0 + j) * 72 + col) * 2) = f2bf(acc[m][n][j]);
        }
#pragma unroll
        for (int n = 4; n < 8; ++n) {                   // K cols 0..63
            int col = (n - 4) * 16 + l15;
#pragma unroll
            for (int j = 0; j < 4; ++j)
                *reinterpret_cast<unsigned short*>(smem + KOFF + ((t0 + j) * 72 + col) * 2) = f2bf(acc[m][n][j]);
        }
#pragma unroll
        for (int n = 8; n < 12; ++n) {                  // VT[h][t], t contiguous in j -> b64
            int h = (n - 8) * 16 + l15;
            ushort4 h4;
            h4.x = f2bf(acc[m][n][0]); h4.y = f2bf(acc[m][n][1]);
            h4.z = f2bf(acc[m][n][2]); h4.w = f2bf(acc[m][n][3]);
            *reinterpret_cast<ushort4*>(smem + VTOFF + (h * 264 + t0) * 2) = h4;
        }
    }
    __syncthreads();

    // ---------------- phase 2: balanced — wave w owns strips {w, 15-w} --------------
    char* Pw = smem + POFF + wid * 4608;                // P[16][72] bf16 / f32 tile [16][68]
    if (wid < 4) {
        attn_strip16<1>(smem, Pw, ob, wid * 16, lane);
        attn_strip16<4>(smem, Pw, ob, (15 - wid) * 16, lane);
    } else {
        attn_strip16<2>(smem, Pw, ob, wid * 16, lane);
        attn_strip16<3>(smem, Pw, ob, (15 - wid) * 16, lane);
    }
}

extern "C" void kernel_launch(void* const* d_in, const int* in_sizes, int n_in,
                              void* d_out, int out_size, void* d_ws, size_t ws_size,
                              hipStream_t stream) {
    const float* x  = (const float*)d_in[0];
    const float* Wq = (const float*)d_in[1];
    const float* Wk = (const float*)d_in[2];
    const float* Wv = (const float*)d_in[3];
    float* out = (float*)d_out;

    unsigned short* Wt2 = (unsigned short*)d_ws;   // [12][4][192][8] bf16 = 147456 B

    wprep<<<288, 256, 0, stream>>>(Wq, Wk, Wv, Wt2);
    fused<<<256, 512, 0, stream>>>(x, Wt2, out);
}

// Round 13
// 37.659 us; speedup vs baseline: 1.0305x; 1.0305x over previous
//
#include <hip/hip_runtime.h>
#include <hip/hip_bf16.h>

typedef __attribute__((ext_vector_type(8))) short bf16x8;
typedef __attribute__((ext_vector_type(4))) float f32x4;

__device__ __forceinline__ unsigned short f2bf(float f) {
    union { float f; unsigned int u; } v; v.f = f;
    unsigned int u = v.u;
    unsigned int r = u + 0x7FFFu + ((u >> 16) & 1u);   // RNE
    return (unsigned short)(r >> 16);
}

__device__ __forceinline__ unsigned int cvtpk(float lo, float hi) {
    unsigned int r;
    asm("v_cvt_pk_bf16_f32 %0, %1, %2" : "=v"(r) : "v"(lo), "v"(hi));
    return r;
}

__device__ __forceinline__ float frcp(float x) {
    float r;
    asm("v_rcp_f32 %0, %1" : "=v"(r) : "v"(x));
    return r;
}

#define GLDS16(gsrc, ldst)                                                          \
    __builtin_amdgcn_global_load_lds(                                               \
        (const __attribute__((address_space(1))) unsigned int*)(gsrc),              \
        (__attribute__((address_space(3))) unsigned int*)(ldst), 16, 0, 0)

// ---------------- kernel 0: W -> Wt2, sigma-permuted k within each 32-chunk --------
// sigma(lg,e) = (e<4?0:16) + lg*4 + (e&3): matches DENSE x loads (lane lg reads
// floats lg*4..lg*4+3 of each 16-float half). MFMA contracts positionally.
__global__ __launch_bounds__(256) void wprep(const float* __restrict__ Wq,
                                             const float* __restrict__ Wk,
                                             const float* __restrict__ Wv,
                                             unsigned short* __restrict__ Wt2) {
    int idx = blockIdx.x * 256 + threadIdx.x;          // 3*64*384 = 73728
    if (idx >= 73728) return;
    int w   = idx / 24576;
    int rem = idx % 24576;
    int n = rem / 384, k = rem % 384;
    const float* W = (w == 0) ? Wq : ((w == 1) ? Wk : Wv);
    int col = w * 64 + n;
    int c = k >> 5, r = k & 31;
    int rr = r & 15;
    int lg = rr >> 2;
    int e  = ((r < 16) ? 0 : 4) + (rr & 3);
    Wt2[(size_t)c * 6144 + lg * 1536 + col * 8 + e] = f2bf(W[k * 64 + n]);
}

#define QOFF  0
#define KOFF  36864
#define VTOFF 73728
#define POFF  107520

// ---------------- phase 2 helper: 16-row strip, NT causal 64-col tiles --------------
template<int NT>
__device__ __forceinline__ void attn_strip16(char* smem, char* Pw, float* __restrict__ ob,
                                             int r0, int lane) {
    const int l15 = lane & 15, lg = lane >> 4;
    const float scale = 0.05103103630798287f;          // 384^-0.5

    bf16x8 aq[2];
#pragma unroll
    for (int kk = 0; kk < 2; ++kk)
        aq[kk] = *reinterpret_cast<const bf16x8*>(smem + QOFF + ((r0 + l15) * 72 + kk * 32 + lg * 8) * 2);

    f32x4 s[NT][4] = {};
#pragma unroll
    for (int jt = 0; jt < NT; ++jt)
#pragma unroll
        for (int kk = 0; kk < 2; ++kk) {
            bf16x8 bk[4];
#pragma unroll
            for (int n = 0; n < 4; ++n)
                bk[n] = *reinterpret_cast<const bf16x8*>(smem + KOFF + ((jt * 64 + n * 16 + l15) * 72 + kk * 32 + lg * 8) * 2);
#pragma unroll
            for (int n = 0; n < 4; ++n)
                s[jt][n] = __builtin_amdgcn_mfma_f32_16x16x32_bf16(aq[kk], bk[n], s[jt][n], 0, 0, 0);
        }

    float M[4];
#pragma unroll
    for (int j = 0; j < 4; ++j) M[j] = -1e30f;
#pragma unroll
    for (int jt = 0; jt < NT; ++jt)
#pragma unroll
        for (int n = 0; n < 4; ++n) {
            int colg = jt * 64 + n * 16 + l15;
#pragma unroll
            for (int j = 0; j < 4; ++j) {
                float v = s[jt][n][j] * scale;
                if (jt == NT - 1) {                     // earlier tiles statically valid
                    int rowg = r0 + lg * 4 + j;
                    if (colg > rowg) v = -1e30f;
                }
                s[jt][n][j] = v;
                M[j] = fmaxf(M[j], v);
            }
        }
#pragma unroll
    for (int j = 0; j < 4; ++j) {
        float v = M[j];
        v = fmaxf(v, __shfl_xor(v, 1));
        v = fmaxf(v, __shfl_xor(v, 2));
        v = fmaxf(v, __shfl_xor(v, 4));
        v = fmaxf(v, __shfl_xor(v, 8));
        M[j] = v;
    }
    float L[4] = {};
#pragma unroll
    for (int jt = 0; jt < NT; ++jt)
#pragma unroll
        for (int n = 0; n < 4; ++n)
#pragma unroll
            for (int j = 0; j < 4; ++j) {
                float p = __expf(s[jt][n][j] - M[j]);
                s[jt][n][j] = p;
                L[j] += p;
            }
    float rL[4];
#pragma unroll
    for (int j = 0; j < 4; ++j) {
        float v = L[j];
        v += __shfl_xor(v, 1);
        v += __shfl_xor(v, 2);
        v += __shfl_xor(v, 4);
        v += __shfl_xor(v, 8);
        rL[j] = frcp(v);
    }
    f32x4 o[4] = {};
#pragma unroll
    for (int jt = 0; jt < NT; ++jt) {
#pragma unroll
        for (int n = 0; n < 4; ++n)
#pragma unroll
            for (int j = 0; j < 4; ++j)
                *reinterpret_cast<unsigned short*>(Pw + ((lg * 4 + j) * 72 + n * 16 + l15) * 2) = f2bf(s[jt][n][j]);
        asm volatile("s_waitcnt lgkmcnt(0)" ::: "memory");   // wave-internal LDS RAW fence
#pragma unroll
        for (int kk = 0; kk < 2; ++kk) {
            bf16x8 ap, bv[4];
            ap = *reinterpret_cast<const bf16x8*>(Pw + (l15 * 72 + kk * 32 + lg * 8) * 2);
#pragma unroll
            for (int n = 0; n < 4; ++n)
                bv[n] = *reinterpret_cast<const bf16x8*>(smem + VTOFF + ((n * 16 + l15) * 264 + jt * 64 + kk * 32 + lg * 8) * 2);
#pragma unroll
            for (int n = 0; n < 4; ++n)
                o[n] = __builtin_amdgcn_mfma_f32_16x16x32_bf16(ap, bv[n], o[n], 0, 0, 0);
        }
    }
    // coalesced epilogue via padded f32 LDS tile (reuses Pw)
    float* tf = reinterpret_cast<float*>(Pw);
#pragma unroll
    for (int n = 0; n < 4; ++n)
#pragma unroll
        for (int j = 0; j < 4; ++j)
            tf[(lg * 4 + j) * 68 + n * 16 + l15] = o[n][j] * rL[j];
    asm volatile("s_waitcnt lgkmcnt(0)" ::: "memory");
#pragma unroll
    for (int i = 0; i < 4; ++i) {
        int row = i * 4 + lg;
        float4 vv = *reinterpret_cast<const float4*>(&tf[row * 68 + l15 * 4]);
        *reinterpret_cast<float4*>(ob + (size_t)(r0 + row) * 64 + l15 * 4) = vv;
    }
}

// ---------------- fused kernel: one block per batch, 512 threads / 8 waves ----------
// Phase 1: barrier-free K-loop, B LDS-resident, x 3-deep reg pipeline (counted
// vmcnt), and NEW: B-fragments software-pipelined through registers (bL/bH) —
// each half-chunk's 6 ds_reads issue one MFMA-cluster EARLY so LDS latency
// hides under MFMA issue instead of sitting on the per-chunk critical path.
__global__ __launch_bounds__(512, 1) void fused(const float* __restrict__ x,
                                                const unsigned short* __restrict__ Wt2,
                                                float* __restrict__ out) {
    __shared__ __align__(16) char smem[147456];

    const int b = blockIdx.x;
    const int tid = threadIdx.x, lane = tid & 63, wid = tid >> 6;   // wid 0..7
    const int l15 = lane & 15, lg = lane >> 4;
    const float* xb = x + (size_t)b * 98304;
    float* ob = out + (size_t)b * 16384;

    // ---- stage ALL of B once: 18 glds/wave, linear ----
#pragma unroll
    for (int i = 0; i < 18; ++i) {
        int n = wid * 18 + i;
        GLDS16(Wt2 + (size_t)n * 512 + lane * 8, smem + n * 1024);
    }

    // ---- x pointer: DENSE loads — lane lg covers floats lg*4..lg*4+3 per 16-half
    const float* xw = xb + (size_t)(wid * 32 + l15) * 384 + lg * 4;

    float4 p0[4], p1[4], p2[4];
#define XLOAD(P, C)                                                                 \
    P[0] = *reinterpret_cast<const float4*>(xw + (C) * 32);                         \
    P[1] = *reinterpret_cast<const float4*>(xw + (C) * 32 + 16);                    \
    P[2] = *reinterpret_cast<const float4*>(xw + 6144 + (C) * 32);                  \
    P[3] = *reinterpret_cast<const float4*>(xw + 6144 + (C) * 32 + 16);
    XLOAD(p0, 0)
    XLOAD(p1, 1)
    XLOAD(p2, 2)
    __builtin_amdgcn_sched_barrier(0);
    asm volatile("s_waitcnt vmcnt(12)" ::: "memory");   // 18 B glds landed; x 0..2 in flight
    __builtin_amdgcn_s_barrier();                       // B visible to all waves

    // ---- prologue B-frag prefetch: LOW(0) ----
    bf16x8 bL[6], bH[6];
    {
        const char* bs0 = smem + lg * 3072 + l15 * 16;
#pragma unroll
        for (int i = 0; i < 6; ++i)
            bL[i] = *reinterpret_cast<const bf16x8*>(bs0 + i * 256);
    }

    f32x4 acc[2][12] = {};

#define CHUNK(C, P, WAITN)                                                          \
    {                                                                               \
        const char* bsc = smem + (C) * 12288 + lg * 3072 + l15 * 16;                \
        _Pragma("unroll")                                                           \
        for (int i = 0; i < 6; ++i)                                                 \
            bH[i] = *reinterpret_cast<const bf16x8*>(bsc + (6 + i) * 256);          \
        asm volatile("s_waitcnt vmcnt(" #WAITN ")" ::: "memory");                   \
        __builtin_amdgcn_sched_barrier(0);                                          \
        union { unsigned int u[4]; bf16x8 v; } cv0, cv1;                            \
        cv0.u[0] = cvtpk(P[0].x, P[0].y); cv0.u[1] = cvtpk(P[0].z, P[0].w);         \
        cv0.u[2] = cvtpk(P[1].x, P[1].y); cv0.u[3] = cvtpk(P[1].z, P[1].w);         \
        cv1.u[0] = cvtpk(P[2].x, P[2].y); cv1.u[1] = cvtpk(P[2].z, P[2].w);         \
        cv1.u[2] = cvtpk(P[3].x, P[3].y); cv1.u[3] = cvtpk(P[3].z, P[3].w);         \
        bf16x8 a0 = cv0.v, a1 = cv1.v;                                              \
        if ((C) + 3 < 12) { XLOAD(P, (C) + 3) }                                     \
        __builtin_amdgcn_sched_barrier(0);                                          \
        _Pragma("unroll")                                                           \
        for (int n = 0; n < 6; ++n) {                                               \
            acc[0][n] = __builtin_amdgcn_mfma_f32_16x16x32_bf16(a0, bL[n], acc[0][n], 0, 0, 0); \
            acc[1][n] = __builtin_amdgcn_mfma_f32_16x16x32_bf16(a1, bL[n], acc[1][n], 0, 0, 0); \
        }                                                                           \
        if ((C) < 11) {                                                             \
            const char* bsn = smem + ((C) + 1) * 12288 + lg * 3072 + l15 * 16;      \
            _Pragma("unroll")                                                       \
            for (int i = 0; i < 6; ++i)                                             \
                bL[i] = *reinterpret_cast<const bf16x8*>(bsn + i * 256);            \
        }                                                                           \
        _Pragma("unroll")                                                           \
        for (int n = 0; n < 6; ++n) {                                               \
            acc[0][6 + n] = __builtin_amdgcn_mfma_f32_16x16x32_bf16(a0, bH[n], acc[0][6 + n], 0, 0, 0); \
            acc[1][6 + n] = __builtin_amdgcn_mfma_f32_16x16x32_bf16(a1, bH[n], acc[1][6 + n], 0, 0, 0); \
        }                                                                           \
    }

    CHUNK(0,  p0, 8)
    CHUNK(1,  p1, 8)
    CHUNK(2,  p2, 8)
    CHUNK(3,  p0, 8)
    CHUNK(4,  p1, 8)
    CHUNK(5,  p2, 8)
    CHUNK(6,  p0, 8)
    CHUNK(7,  p1, 8)
    CHUNK(8,  p2, 8)
    CHUNK(9,  p0, 8)
    CHUNK(10, p1, 4)
    CHUNK(11, p2, 0)

    __syncthreads();                                    // all waves done reading B

    // ---- stage Q/K/VT to LDS (C/D layout: col=l15, row=lg*4+j) ----
#pragma unroll
    for (int m = 0; m < 2; ++m) {
        const int t0 = wid * 32 + m * 16 + lg * 4;
#pragma unroll
        for (int n = 0; n < 4; ++n) {                   // Q cols 0..63
            int col = n * 16 + l15;
#pragma unroll
            for (int j = 0; j < 4; ++j)
                *reinterpret_cast<unsigned short*>(smem + QOFF + ((t0 + j) * 72 + col) * 2) = f2bf(acc[m][n][j]);
        }
#pragma unroll
        for (int n = 4; n < 8; ++n) {                   // K cols 0..63
            int col = (n - 4) * 16 + l15;
#pragma unroll
            for (int j = 0; j < 4; ++j)
                *reinterpret_cast<unsigned short*>(smem + KOFF + ((t0 + j) * 72 + col) * 2) = f2bf(acc[m][n][j]);
        }
#pragma unroll
        for (int n = 8; n < 12; ++n) {                  // VT[h][t], t contiguous in j -> b64
            int h = (n - 8) * 16 + l15;
            ushort4 h4;
            h4.x = f2bf(acc[m][n][0]); h4.y = f2bf(acc[m][n][1]);
            h4.z = f2bf(acc[m][n][2]); h4.w = f2bf(acc[m][n][3]);
            *reinterpret_cast<ushort4*>(smem + VTOFF + (h * 264 + t0) * 2) = h4;
        }
    }
    __syncthreads();

    // ---------------- phase 2: balanced — wave w owns strips {w, 15-w} --------------
    char* Pw = smem + POFF + wid * 4608;                // P[16][72] bf16 / f32 tile [16][68]
    if (wid < 4) {
        attn_strip16<1>(smem, Pw, ob, wid * 16, lane);
        attn_strip16<4>(smem, Pw, ob, (15 - wid) * 16, lane);
    } else {
        attn_strip16<2>(smem, Pw, ob, wid * 16, lane);
        attn_strip16<3>(smem, Pw, ob, (15 - wid) * 16, lane);
    }
}

extern "C" void kernel_launch(void* const* d_in, const int* in_sizes, int n_in,
                              void* d_out, int out_size, void* d_ws, size_t ws_size,
                              hipStream_t stream) {
    const float* x  = (const float*)d_in[0];
    const float* Wq = (const float*)d_in[1];
    const float* Wk = (const float*)d_in[2];
    const float* Wv = (const float*)d_in[3];
    float* out = (float*)d_out;

    unsigned short* Wt2 = (unsigned short*)d_ws;   // [12][4][192][8] bf16 = 147456 B

    wprep<<<288, 256, 0, stream>>>(Wq, Wk, Wv, Wt2);
    fused<<<256, 512, 0, stream>>>(x, Wt2, out);
}